// Round 1
// baseline (6966.002 us; speedup 1.0000x reference)
//
#include <hip/hip_runtime.h>

// ---------------------------------------------------------------------------
// Adaptive-attention LSTM decoder (B=128, P=49, D=E=A=512, V=10000, T=50).
// Strategy:
//  * Precompute (batched over all 49 steps): xw=[emb;gi] -> P1 (LSTM1 input-side
//    gates + biases), Ps (sentinel input-side + biases), visual_att.
//  * Sequential scan: 6 small MFMA kernels per step, stream-ordered.
//  * Final: one big fc GEMM over all stored h2 states.
// All GEMMs: bf16 MFMA 16x16x32, fp32 accumulate. States m1/m2 fp32.
// P1/Ps/va scratch lives in d_out (overwritten by fc at the end).
// ---------------------------------------------------------------------------

typedef unsigned short u16;
typedef short bf16x8 __attribute__((ext_vector_type(8)));
typedef float f32x4 __attribute__((ext_vector_type(4)));

#define MFMA16(a, b, c) __builtin_amdgcn_mfma_f32_16x16x32_bf16(a, b, c, 0, 0, 0)

__device__ __forceinline__ u16 f2bf(float f) {
    union { float f; unsigned u; } v; v.f = f;
    return (u16)((v.u + 0x7fffu + ((v.u >> 16) & 1u)) >> 16);
}
__device__ __forceinline__ float bf2f(u16 h) {
    union { unsigned u; float f; } v; v.u = ((unsigned)h) << 16; return v.f;
}
__device__ __forceinline__ float sigm(float x) {
    x = fminf(fmaxf(x, -30.f), 30.f);
    return 1.f / (1.f + __expf(-x));
}
__device__ __forceinline__ float tanh_(float x) {
    x = fminf(fmaxf(x, -15.f), 15.f);
    float e = __expf(2.f * x);
    return (e - 1.f) / (e + 1.f);
}

// Wave computes 2 m-tiles x up to 4 n-tiles of C = A @ W^T.
// A: [M][K] bf16 row-major, optionally split in K at `asplit` (A0 then A1).
// W: [N][K] bf16 row-major. K, asplit multiples of 32.
__device__ __forceinline__ void gemm_2x4(const u16* __restrict__ A0, const u16* __restrict__ A1,
                                         int asplit, int lda0, int lda1,
                                         const u16* __restrict__ W, int ldw, int K,
                                         int m_base, int n_base, int nt, f32x4 acc[2][4]) {
    const int lane = threadIdx.x & 63, r = lane & 15, lg = lane >> 4;
    for (int k0 = 0; k0 < K; k0 += 32) {
        int kk = k0 + lg * 8;
        const u16* Ab; int ka, lda;
        if (k0 < asplit) { Ab = A0; ka = kk; lda = lda0; }
        else             { Ab = A1; ka = kk - asplit; lda = lda1; }
        bf16x8 a0 = *(const bf16x8*)(Ab + (size_t)(m_base + r) * lda + ka);
        bf16x8 a1 = *(const bf16x8*)(Ab + (size_t)(m_base + 16 + r) * lda + ka);
#pragma unroll
        for (int j = 0; j < 4; ++j) {
            if (j < nt) {
                bf16x8 wf = *(const bf16x8*)(W + (size_t)(n_base + j * 16 + r) * ldw + kk);
                acc[0][j] = MFMA16(a0, wf, acc[0][j]);
                acc[1][j] = MFMA16(a1, wf, acc[1][j]);
            }
        }
    }
}

// ---------------- one-time conversion / packing kernels ----------------

__global__ __launch_bounds__(256) void k_cvt(const float* __restrict__ s, u16* __restrict__ d, int n) {
    int i = blockIdx.x * 256 + threadIdx.x;
    if (i < n) d[i] = f2bf(s[i]);
}

// dst[n][k] = (k < wA) ? A[n*ldA + offA + k] : B[n*ldB + (k - wA)]
__global__ __launch_bounds__(256) void k_pack(const float* __restrict__ A, int ldA, int offA, int wA,
                                              const float* __restrict__ Bs, int ldB,
                                              u16* __restrict__ dst, int Ktot, int total) {
    int i = blockIdx.x * 256 + threadIdx.x;
    if (i >= total) return;
    int n = i / Ktot, k = i - n * Ktot;
    float v = (k < wA) ? A[(size_t)n * ldA + offA + k] : Bs[(size_t)n * ldB + (k - wA)];
    dst[i] = f2bf(v);
}

// xw[t][b][k] : k<512 -> emb[cap[b][t]][k], else global_image[b][k-512]
__global__ __launch_bounds__(256) void k_xw(const float* __restrict__ emb, const float* __restrict__ gimg,
                                            const int* __restrict__ cap, u16* __restrict__ XW, int total) {
    int i = blockIdx.x * 256 + threadIdx.x;
    if (i >= total) return;
    int t = i >> 17;                 // /(128*1024)
    int rem = i & ((1 << 17) - 1);
    int b = rem >> 10, k = rem & 1023;
    float v = (k < 512) ? emb[(size_t)cap[b * 50 + t] * 512 + k] : gimg[b * 512 + (k - 512)];
    XW[i] = f2bf(v);
}

// ---------------- batched precompute GEMMs ----------------

// P1[t*128+b][2048] = xw @ W1X^T + b_ih1 + b_hh1 ; Ps[...][512] = xw @ WSX^T + s_bx + s_bh
__global__ __launch_bounds__(256) void k_p1ps(const u16* __restrict__ XW, const u16* __restrict__ W1X,
                                              const u16* __restrict__ WSX,
                                              const float* __restrict__ b_ih1, const float* __restrict__ b_hh1,
                                              const float* __restrict__ s_bx, const float* __restrict__ s_bh,
                                              float* __restrict__ P1, float* __restrict__ PS) {
    int bid = blockIdx.x;
    int ng = bid % 40, mg = bid / 40;
    int w = threadIdx.x >> 6, lane = threadIdx.x & 63, r = lane & 15, lg = lane >> 4;
    int m_base = mg * 128 + w * 32;
    f32x4 acc[2][4] = {};
    if (ng < 32) {
        int n_base = ng * 64;
        gemm_2x4(XW, XW, 1 << 28, 1024, 1024, W1X, 1024, 1024, m_base, n_base, 4, acc);
#pragma unroll
        for (int mt = 0; mt < 2; ++mt)
#pragma unroll
            for (int j = 0; j < 4; ++j)
#pragma unroll
                for (int reg = 0; reg < 4; ++reg) {
                    int row = m_base + mt * 16 + lg * 4 + reg;
                    int col = n_base + j * 16 + r;
                    P1[(size_t)row * 2048 + col] = acc[mt][j][reg] + b_ih1[col] + b_hh1[col];
                }
    } else {
        int n_base = (ng - 32) * 64;
        gemm_2x4(XW, XW, 1 << 28, 1024, 1024, WSX, 1024, 1024, m_base, n_base, 4, acc);
#pragma unroll
        for (int mt = 0; mt < 2; ++mt)
#pragma unroll
            for (int j = 0; j < 4; ++j)
#pragma unroll
                for (int reg = 0; reg < 4; ++reg) {
                    int row = m_base + mt * 16 + lg * 4 + reg;
                    int col = n_base + j * 16 + r;
                    PS[(size_t)row * 512 + col] = acc[mt][j][reg] + s_bx[col] + s_bh[col];
                }
    }
}

// va[b*49+p][512] = spatial @ wv^T + wv_b
__global__ __launch_bounds__(256) void k_va(const u16* __restrict__ SPB, const u16* __restrict__ WVB,
                                            const float* __restrict__ wv_b, float* __restrict__ VA) {
    int bid = blockIdx.x;
    int ng = bid % 8, mg = bid / 8;
    int w = threadIdx.x >> 6, lane = threadIdx.x & 63, r = lane & 15, lg = lane >> 4;
    int m_base = mg * 128 + w * 32;
    int n_base = ng * 64;
    f32x4 acc[2][4] = {};
    gemm_2x4(SPB, SPB, 1 << 28, 512, 512, WVB, 512, 512, m_base, n_base, 4, acc);
#pragma unroll
    for (int mt = 0; mt < 2; ++mt)
#pragma unroll
        for (int j = 0; j < 4; ++j)
#pragma unroll
            for (int reg = 0; reg < 4; ++reg) {
                int row = m_base + mt * 16 + lg * 4 + reg;
                int col = n_base + j * 16 + r;
                VA[(size_t)row * 512 + col] = acc[mt][j][reg] + wv_b[col];
            }
}

// ---------------- per-step kernels ----------------

// Phase 1: LSTM1 gates + sentinel gate, fused cell update.
// A = [h2 (k<512) | h1_cur (k>=512)], W1H = [w_ih1[:, :512] | w_hh1] (2048x1024),
// WSH = [s_wx[:, :512] | s_wh] (512x1024). Adds P1[t], Ps[t].
__global__ __launch_bounds__(256) void k_lstm1(const u16* __restrict__ H2BF, const u16* __restrict__ H1C,
                                               const u16* __restrict__ W1H, const u16* __restrict__ WSH,
                                               const float* __restrict__ P1, const float* __restrict__ PS,
                                               float* __restrict__ M1, u16* __restrict__ H1N,
                                               u16* __restrict__ STBF, int t) {
    int d0 = blockIdx.x * 16;  // 32 blocks cover d = 0..511
    int w = threadIdx.x >> 6, lane = threadIdx.x & 63, r = lane & 15, lg = lane >> 4;
    int m_base = w * 32;
    f32x4 acc[2][5] = {};
    for (int k0 = 0; k0 < 1024; k0 += 32) {
        int kk = k0 + lg * 8;
        const u16* Ab = (k0 < 512) ? H2BF : H1C;
        int ka = (k0 < 512) ? kk : kk - 512;
        bf16x8 a0 = *(const bf16x8*)(Ab + (size_t)(m_base + r) * 512 + ka);
        bf16x8 a1 = *(const bf16x8*)(Ab + (size_t)(m_base + 16 + r) * 512 + ka);
#pragma unroll
        for (int gt = 0; gt < 4; ++gt) {
            bf16x8 wf = *(const bf16x8*)(W1H + (size_t)(gt * 512 + d0 + r) * 1024 + kk);
            acc[0][gt] = MFMA16(a0, wf, acc[0][gt]);
            acc[1][gt] = MFMA16(a1, wf, acc[1][gt]);
        }
        bf16x8 wsf = *(const bf16x8*)(WSH + (size_t)(d0 + r) * 1024 + kk);
        acc[0][4] = MFMA16(a0, wsf, acc[0][4]);
        acc[1][4] = MFMA16(a1, wsf, acc[1][4]);
    }
    int d = d0 + r;
#pragma unroll
    for (int mt = 0; mt < 2; ++mt)
#pragma unroll
        for (int reg = 0; reg < 4; ++reg) {
            int row = m_base + mt * 16 + lg * 4 + reg;
            const float* p1r = P1 + ((size_t)t * 128 + row) * 2048;
            float gi = acc[mt][0][reg] + p1r[d];
            float gf = acc[mt][1][reg] + p1r[512 + d];
            float gg = acc[mt][2][reg] + p1r[1024 + d];
            float go = acc[mt][3][reg] + p1r[1536 + d];
            float gs = acc[mt][4][reg] + PS[((size_t)t * 128 + row) * 512 + d];
            int idx = row * 512 + d;
            float m1o = M1[idx];
            float m1n = sigm(gf) * m1o + sigm(gi) * tanh_(gg);
            float h1n = sigm(go) * tanh_(m1n);
            float st  = sigm(gs) * tanh_(m1n);
            M1[idx] = m1n;
            H1N[idx] = f2bf(h1n);
            STBF[idx] = f2bf(st);
        }
}

// Phase 2: s2 = relu(s_t@aff_s^T+b), ht = tanh(h1n@aff_h^T+b), g2p = [h1n|h2]@W2H^T
__global__ __launch_bounds__(256) void k_ph2(const u16* __restrict__ STBF, const u16* __restrict__ H1N,
                                             const u16* __restrict__ H2BF,
                                             const u16* __restrict__ AFFS, const u16* __restrict__ AFFH,
                                             const u16* __restrict__ W2H,
                                             const float* __restrict__ affs_b, const float* __restrict__ affh_b,
                                             u16* __restrict__ S2BF, float* __restrict__ HTF,
                                             u16* __restrict__ HTBF, float* __restrict__ G2P) {
    int bid = blockIdx.x;
    int w = threadIdx.x >> 6, lane = threadIdx.x & 63, r = lane & 15, lg = lane >> 4;
    int m_base = w * 32;
    f32x4 acc[2][4] = {};
    if (bid < 8) {
        int n_base = bid * 64;
        gemm_2x4(STBF, STBF, 1 << 28, 512, 512, AFFS, 512, 512, m_base, n_base, 4, acc);
#pragma unroll
        for (int mt = 0; mt < 2; ++mt)
#pragma unroll
            for (int j = 0; j < 4; ++j)
#pragma unroll
                for (int reg = 0; reg < 4; ++reg) {
                    int row = m_base + mt * 16 + lg * 4 + reg;
                    int col = n_base + j * 16 + r;
                    float v = acc[mt][j][reg] + affs_b[col];
                    S2BF[row * 512 + col] = f2bf(fmaxf(v, 0.f));
                }
    } else if (bid < 16) {
        int n_base = (bid - 8) * 64;
        gemm_2x4(H1N, H1N, 1 << 28, 512, 512, AFFH, 512, 512, m_base, n_base, 4, acc);
#pragma unroll
        for (int mt = 0; mt < 2; ++mt)
#pragma unroll
            for (int j = 0; j < 4; ++j)
#pragma unroll
                for (int reg = 0; reg < 4; ++reg) {
                    int row = m_base + mt * 16 + lg * 4 + reg;
                    int col = n_base + j * 16 + r;
                    float v = tanh_(acc[mt][j][reg] + affh_b[col]);
                    HTF[row * 512 + col] = v;
                    HTBF[row * 512 + col] = f2bf(v);
                }
    } else {
        int n_base = (bid - 16) * 64;
        gemm_2x4(H1N, H2BF, 512, 512, 512, W2H, 1024, 1024, m_base, n_base, 4, acc);
#pragma unroll
        for (int mt = 0; mt < 2; ++mt)
#pragma unroll
            for (int j = 0; j < 4; ++j)
#pragma unroll
                for (int reg = 0; reg < 4; ++reg) {
                    int row = m_base + mt * 16 + lg * 4 + reg;
                    int col = n_base + j * 16 + r;
                    G2P[row * 2048 + col] = acc[mt][j][reg];
                }
    }
}

// Phase 3: hid = ht@wg^T + wg_b ; sen = s2@ws^T + ws_b
__global__ __launch_bounds__(256) void k_ph3(const u16* __restrict__ HTBF, const u16* __restrict__ S2BF,
                                             const u16* __restrict__ WGB, const u16* __restrict__ WSB,
                                             const float* __restrict__ wg_b, const float* __restrict__ ws_b,
                                             float* __restrict__ HID, float* __restrict__ SEN) {
    int bid = blockIdx.x;
    int w = threadIdx.x >> 6, lane = threadIdx.x & 63, r = lane & 15, lg = lane >> 4;
    int m_base = w * 32;
    f32x4 acc[2][4] = {};
    const u16* A = (bid < 8) ? HTBF : S2BF;
    const u16* W = (bid < 8) ? WGB : WSB;
    const float* bb = (bid < 8) ? wg_b : ws_b;
    float* out = (bid < 8) ? HID : SEN;
    int n_base = (bid & 7) * 64;
    gemm_2x4(A, A, 1 << 28, 512, 512, W, 512, 512, m_base, n_base, 4, acc);
#pragma unroll
    for (int mt = 0; mt < 2; ++mt)
#pragma unroll
        for (int j = 0; j < 4; ++j)
#pragma unroll
            for (int reg = 0; reg < 4; ++reg) {
                int row = m_base + mt * 16 + lg * 4 + reg;
                int col = n_base + j * 16 + r;
                out[row * 512 + col] = acc[mt][j][reg] + bb[col];
            }
}

// Phase 4: z -> softmax -> c_hat ; chh = c_hat + ht (bf16). One block per batch row.
__global__ __launch_bounds__(256) void k_attn(const float* __restrict__ VA, const float* __restrict__ SEN,
                                              const float* __restrict__ HID, const float* __restrict__ whw,
                                              const float* __restrict__ whb, const float* __restrict__ SF,
                                              const u16* __restrict__ S2BF, const float* __restrict__ HTF,
                                              u16* __restrict__ CHHBF) {
    __shared__ float hidL[512], whwL[512], zbuf[50], albuf[50];
    int b = blockIdx.x, tid = threadIdx.x;
    for (int i = tid; i < 512; i += 256) { hidL[i] = HID[b * 512 + i]; whwL[i] = whw[i]; }
    __syncthreads();
    int w = tid >> 6, lane = tid & 63;
    for (int p = w; p < 50; p += 4) {
        const float* src = (p < 49) ? (VA + ((size_t)b * 49 + p) * 512) : (SEN + (size_t)b * 512);
        float part = 0.f;
#pragma unroll
        for (int it = 0; it < 8; ++it) {
            int a = lane + it * 64;
            part += tanh_(src[a] + hidL[a]) * whwL[a];
        }
#pragma unroll
        for (int off2 = 32; off2; off2 >>= 1) part += __shfl_xor(part, off2, 64);
        if (lane == 0) zbuf[p] = part + whb[0];
    }
    __syncthreads();
    if (tid < 64) {
        float v = (tid < 50) ? zbuf[tid] : -1e30f;
        float mx = v;
#pragma unroll
        for (int off2 = 32; off2; off2 >>= 1) mx = fmaxf(mx, __shfl_xor(mx, off2, 64));
        float e = (tid < 50) ? __expf(v - mx) : 0.f;
        float s = e;
#pragma unroll
        for (int off2 = 32; off2; off2 >>= 1) s += __shfl_xor(s, off2, 64);
        if (tid < 50) albuf[tid] = e / s;
    }
    __syncthreads();
    float a49 = albuf[49];
    for (int d = tid; d < 512; d += 256) {
        float acc = a49 * bf2f(S2BF[b * 512 + d]);
        for (int p = 0; p < 49; ++p) acc += albuf[p] * SF[((size_t)b * 49 + p) * 512 + d];
        float chh = acc + HTF[b * 512 + d];
        CHHBF[b * 512 + d] = f2bf(chh);
    }
}

// Phase 4b: att_out = tanh(chh@wp^T + wp_b) -> bf16
__global__ __launch_bounds__(256) void k_ph4b(const u16* __restrict__ CHHBF, const u16* __restrict__ WPB,
                                              const float* __restrict__ wp_b, u16* __restrict__ ATTBF) {
    int bid = blockIdx.x;
    int w = threadIdx.x >> 6, lane = threadIdx.x & 63, r = lane & 15, lg = lane >> 4;
    int m_base = w * 32;
    int n_base = bid * 64;
    f32x4 acc[2][4] = {};
    gemm_2x4(CHHBF, CHHBF, 1 << 28, 512, 512, WPB, 512, 512, m_base, n_base, 4, acc);
#pragma unroll
    for (int mt = 0; mt < 2; ++mt)
#pragma unroll
        for (int j = 0; j < 4; ++j)
#pragma unroll
            for (int reg = 0; reg < 4; ++reg) {
                int row = m_base + mt * 16 + lg * 4 + reg;
                int col = n_base + j * 16 + r;
                ATTBF[row * 512 + col] = f2bf(tanh_(acc[mt][j][reg] + wp_b[col]));
            }
}

// Phase 5: LSTM2. g2 = g2p + att_out@W2A^T + b_ih2 + b_hh2 -> h2n, m2n; store H2all[t].
__global__ __launch_bounds__(256) void k_lstm2(const u16* __restrict__ ATTBF, const u16* __restrict__ W2A,
                                               const float* __restrict__ G2P,
                                               const float* __restrict__ b_ih2, const float* __restrict__ b_hh2,
                                               float* __restrict__ M2, u16* __restrict__ H2BF,
                                               u16* __restrict__ H2ALL, int t) {
    int d0 = blockIdx.x * 16;
    int w = threadIdx.x >> 6, lane = threadIdx.x & 63, r = lane & 15, lg = lane >> 4;
    int m_base = w * 32;
    f32x4 acc[2][4] = {};
    for (int k0 = 0; k0 < 512; k0 += 32) {
        int kk = k0 + lg * 8;
        bf16x8 a0 = *(const bf16x8*)(ATTBF + (size_t)(m_base + r) * 512 + kk);
        bf16x8 a1 = *(const bf16x8*)(ATTBF + (size_t)(m_base + 16 + r) * 512 + kk);
#pragma unroll
        for (int gt = 0; gt < 4; ++gt) {
            bf16x8 wf = *(const bf16x8*)(W2A + (size_t)(gt * 512 + d0 + r) * 512 + kk);
            acc[0][gt] = MFMA16(a0, wf, acc[0][gt]);
            acc[1][gt] = MFMA16(a1, wf, acc[1][gt]);
        }
    }
    int d = d0 + r;
#pragma unroll
    for (int mt = 0; mt < 2; ++mt)
#pragma unroll
        for (int reg = 0; reg < 4; ++reg) {
            int row = m_base + mt * 16 + lg * 4 + reg;
            const float* g2r = G2P + (size_t)row * 2048;
            float gi = acc[mt][0][reg] + g2r[d]        + b_ih2[d]        + b_hh2[d];
            float gf = acc[mt][1][reg] + g2r[512 + d]  + b_ih2[512 + d]  + b_hh2[512 + d];
            float gg = acc[mt][2][reg] + g2r[1024 + d] + b_ih2[1024 + d] + b_hh2[1024 + d];
            float go = acc[mt][3][reg] + g2r[1536 + d] + b_ih2[1536 + d] + b_hh2[1536 + d];
            int idx = row * 512 + d;
            float m2n = sigm(gf) * M2[idx] + sigm(gi) * tanh_(gg);
            float h2n = sigm(go) * tanh_(m2n);
            M2[idx] = m2n;
            u16 hb = f2bf(h2n);
            H2BF[idx] = hb;
            H2ALL[((size_t)t * 128 + row) * 512 + d] = hb;
        }
}

// Final: preds[b][t][v] = H2all[t*128+b] @ fc_w^T + fc_b
__global__ __launch_bounds__(256) void k_fc(const u16* __restrict__ H2ALL, const u16* __restrict__ FCB,
                                            const float* __restrict__ fc_b, float* __restrict__ out) {
    int bid = blockIdx.x;
    int ng = bid % 157, mg = bid / 157;
    int w = threadIdx.x >> 6, lane = threadIdx.x & 63, r = lane & 15, lg = lane >> 4;
    int m_base = mg * 128 + w * 32;
    int n_base = ng * 64;
    int nt = (10000 - n_base) / 16; if (nt > 4) nt = 4;
    f32x4 acc[2][4] = {};
    gemm_2x4(H2ALL, H2ALL, 1 << 28, 512, 512, FCB, 512, 512, m_base, n_base, nt, acc);
#pragma unroll
    for (int mt = 0; mt < 2; ++mt)
#pragma unroll
        for (int j = 0; j < 4; ++j) {
            if (j < nt) {
#pragma unroll
                for (int reg = 0; reg < 4; ++reg) {
                    int row = m_base + mt * 16 + lg * 4 + reg;
                    int col = n_base + j * 16 + r;
                    int t = row >> 7, b = row & 127;
                    out[((size_t)b * 49 + t) * 10000 + col] = acc[mt][j][reg] + fc_b[col];
                }
            }
        }
}

// ---------------------------------------------------------------------------

extern "C" void kernel_launch(void* const* d_in, const int* in_sizes, int n_in,
                              void* d_out, int out_size, void* d_ws, size_t ws_size,
                              hipStream_t stream) {
    (void)in_sizes; (void)n_in; (void)out_size; (void)ws_size;

    const float* SF      = (const float*)d_in[0];   // (128,49,512)
    const float* GIMG    = (const float*)d_in[1];   // (128,512)
    const int*   CAP     = (const int*)d_in[2];     // (128,50)
    const float* EMB     = (const float*)d_in[4];   // (10000,512)
    const float* w_ih1   = (const float*)d_in[5];   // (2048,1536)
    const float* w_hh1   = (const float*)d_in[6];   // (2048,512)
    const float* b_ih1   = (const float*)d_in[7];
    const float* b_hh1   = (const float*)d_in[8];
    const float* s_wx    = (const float*)d_in[9];   // (512,1536)
    const float* s_bx    = (const float*)d_in[10];
    const float* s_wh    = (const float*)d_in[11];  // (512,512)
    const float* s_bh    = (const float*)d_in[12];
    const float* w_ih2   = (const float*)d_in[13];  // (2048,1024)
    const float* w_hh2   = (const float*)d_in[14];  // (2048,512)
    const float* b_ih2   = (const float*)d_in[15];
    const float* b_hh2   = (const float*)d_in[16];
    const float* aff_s_w = (const float*)d_in[17];
    const float* aff_s_b = (const float*)d_in[18];
    const float* aff_h_w = (const float*)d_in[19];
    const float* aff_h_b = (const float*)d_in[20];
    const float* ws_w    = (const float*)d_in[21];
    const float* ws_b    = (const float*)d_in[22];
    const float* wg_w    = (const float*)d_in[23];
    const float* wg_b    = (const float*)d_in[24];
    const float* wv_w    = (const float*)d_in[25];
    const float* wv_b    = (const float*)d_in[26];
    const float* wh_w    = (const float*)d_in[27];  // (1,512)
    const float* wh_b    = (const float*)d_in[28];  // (1,)
    const float* wp_w    = (const float*)d_in[29];
    const float* wp_b    = (const float*)d_in[30];
    const float* fc_w    = (const float*)d_in[31];  // (10000,512)
    const float* fc_b    = (const float*)d_in[32];

    float* out = (float*)d_out;

    // big fp32 scratch lives in d_out (fc overwrites all of d_out at the end)
    float* P1 = out;                      // 49*128*2048 = 12,845,056 floats
    float* PS = out + 12845056;           //  3,211,264 floats
    float* VA = out + 16056320;           //  3,211,264 floats (total 19.27M < 62.72M)

    char* ws = (char*)d_ws;
    size_t off = 0;
    auto alloc = [&](size_t elts, size_t esz) -> void* {
        void* p = ws + off;
        off += (elts * esz + 255) & ~(size_t)255;
        return p;
    };
    u16* W1H   = (u16*)alloc(2048 * 1024, 2);
    u16* WSH   = (u16*)alloc(512 * 1024, 2);
    u16* W1X   = (u16*)alloc(2048 * 1024, 2);
    u16* WSX   = (u16*)alloc(512 * 1024, 2);
    u16* W2A   = (u16*)alloc(2048 * 512, 2);
    u16* W2H   = (u16*)alloc(2048 * 1024, 2);
    u16* AFFS  = (u16*)alloc(262144, 2);
    u16* AFFH  = (u16*)alloc(262144, 2);
    u16* WSB   = (u16*)alloc(262144, 2);
    u16* WGB   = (u16*)alloc(262144, 2);
    u16* WVB   = (u16*)alloc(262144, 2);
    u16* WPB   = (u16*)alloc(262144, 2);
    u16* FCB   = (u16*)alloc(5120000, 2);
    u16* SPB   = (u16*)alloc(3211264, 2);
    u16* XWB   = (u16*)alloc(6422528, 2);
    u16* H2ALL = (u16*)alloc(3211264, 2);
    u16* H1A   = (u16*)alloc(65536, 2);
    u16* H1B   = (u16*)alloc(65536, 2);
    u16* H2BF  = (u16*)alloc(65536, 2);
    u16* STBF  = (u16*)alloc(65536, 2);
    u16* S2BF  = (u16*)alloc(65536, 2);
    u16* HTBF  = (u16*)alloc(65536, 2);
    u16* CHHBF = (u16*)alloc(65536, 2);
    u16* ATTBF = (u16*)alloc(65536, 2);
    float* M1  = (float*)alloc(65536, 4);
    float* M2  = (float*)alloc(65536, 4);
    float* HTF = (float*)alloc(65536, 4);
    float* HID = (float*)alloc(65536, 4);
    float* SEN = (float*)alloc(65536, 4);
    float* G2P = (float*)alloc(262144, 4);

    // zero-init recurrent state (every call; harness does not re-poison)
    hipMemsetAsync(H1A, 0, 65536 * 2, stream);
    hipMemsetAsync(H2BF, 0, 65536 * 2, stream);
    hipMemsetAsync(M1, 0, 65536 * 4, stream);
    hipMemsetAsync(M2, 0, 65536 * 4, stream);

    auto gs = [](int n) { return (n + 255) / 256; };

    // weight conversions (bf16)
    k_cvt<<<gs(262144), 256, 0, stream>>>(aff_s_w, AFFS, 262144);
    k_cvt<<<gs(262144), 256, 0, stream>>>(aff_h_w, AFFH, 262144);
    k_cvt<<<gs(262144), 256, 0, stream>>>(ws_w, WSB, 262144);
    k_cvt<<<gs(262144), 256, 0, stream>>>(wg_w, WGB, 262144);
    k_cvt<<<gs(262144), 256, 0, stream>>>(wv_w, WVB, 262144);
    k_cvt<<<gs(262144), 256, 0, stream>>>(wp_w, WPB, 262144);
    k_cvt<<<gs(5120000), 256, 0, stream>>>(fc_w, FCB, 5120000);
    k_cvt<<<gs(3211264), 256, 0, stream>>>(SF, SPB, 3211264);

    // packs: [recurrent-side | hidden-side] weight concatenations
    k_pack<<<gs(2097152), 256, 0, stream>>>(w_ih1, 1536, 0, 512, w_hh1, 512, W1H, 1024, 2097152);
    k_pack<<<gs(524288), 256, 0, stream>>>(s_wx, 1536, 0, 512, s_wh, 512, WSH, 1024, 524288);
    k_pack<<<gs(2097152), 256, 0, stream>>>(w_ih1, 1536, 512, 1024, w_ih1, 1536, W1X, 1024, 2097152);
    k_pack<<<gs(524288), 256, 0, stream>>>(s_wx, 1536, 512, 1024, s_wx, 1536, WSX, 1024, 524288);
    k_pack<<<gs(1048576), 256, 0, stream>>>(w_ih2, 1024, 0, 512, w_ih2, 1024, W2A, 512, 1048576);
    k_pack<<<gs(2097152), 256, 0, stream>>>(w_ih2, 1024, 512, 512, w_hh2, 512, W2H, 1024, 2097152);

    // xw = [emb[cap]; global_image] for t=0..48
    k_xw<<<gs(6422528), 256, 0, stream>>>(EMB, GIMG, CAP, XWB, 6422528);

    // batched precompute GEMMs
    k_p1ps<<<49 * 40, 256, 0, stream>>>(XWB, W1X, WSX, b_ih1, b_hh1, s_bx, s_bh, P1, PS);
    k_va<<<49 * 8, 256, 0, stream>>>(SPB, WVB, wv_b, VA);

    // sequential scan
    for (int t = 0; t < 49; ++t) {
        const u16* h1c = (t & 1) ? H1B : H1A;
        u16* h1n = (t & 1) ? H1A : H1B;
        k_lstm1<<<32, 256, 0, stream>>>(H2BF, h1c, W1H, WSH, P1, PS, M1, h1n, STBF, t);
        k_ph2<<<48, 256, 0, stream>>>(STBF, h1n, H2BF, AFFS, AFFH, W2H, aff_s_b, aff_h_b,
                                      S2BF, HTF, HTBF, G2P);
        k_ph3<<<16, 256, 0, stream>>>(HTBF, S2BF, WGB, WSB, wg_b, ws_b, HID, SEN);
        k_attn<<<128, 256, 0, stream>>>(VA, SEN, HID, wh_w, wh_b, SF, S2BF, HTF, CHHBF);
        k_ph4b<<<8, 256, 0, stream>>>(CHHBF, WPB, wp_b, ATTBF);
        k_lstm2<<<32, 256, 0, stream>>>(ATTBF, W2A, G2P, b_ih2, b_hh2, M2, H2BF, H2ALL, t);
    }

    // final projection to vocab
    k_fc<<<49 * 157, 256, 0, stream>>>(H2ALL, FCB, fc_b, out);
}